// Round 8
// baseline (432.258 us; speedup 1.0000x reference)
//
#include <hip/hip_runtime.h>
#include <hip/hip_cooperative_groups.h>
#include <stdint.h>

namespace cg = cooperative_groups;

#define NBATCH   8
#define NA       261888
#define PRE      6000
#define PREP     6016
#define NCHUNK   94
#define OUT_CNT  2000
#define NMS_THR  0.7f
#define NBINS    4096
#define CANDCAP  8192
#define ECAP     8
#define SEGCAP   2048
#define J0       3072     // edges computed only for j < J0; scan falls back past it
#define NJT      12       // J0 / 256
#define NTPE     78       // NJT*(NJT+1)/2 tile-pairs
#define NBLK     512      // cooperative grid size (co-residency guaranteed, see launch_bounds)

// workspace layout (bytes)
#define OFF_HIST     0ull                      // 8*4096*4 = 131072
#define OFF_BCNT     131072ull                 // 8*4096*4 = 131072
#define OFF_CNT      262144ull                 // 8*6016*4 = 192512
#define ZEND         454656ull                 // bytes zeroed each call (28416 uint4)
#define NZB          111
#define OFF_TINFO    454656ull                 // 32
#define OFF_CUM      454688ull                 // 8*4097*4 = 131104
#define OFF_BOXES    585792ull                 // 8*6016*16 = 770048
#define OFF_CANDS    1355840ull                // 8*8192*8 = 524288
#define OFF_EDGES    1355840ull                // overlays candS (dead after binsort)
// total ~2.03 MB

__device__ __forceinline__ int score_bin(float s) {
    int b = (int)(s * 4096.0f);          // *4096 exact (pow2) -> monotone
    return min(max(b, 0), NBINS - 1);
}

__device__ __forceinline__ float iou_of(float4 A, float4 Bv) {
    float ai = (A.z - A.x) * (A.w - A.y);
    float aj = (Bv.z - Bv.x) * (Bv.w - Bv.y);
    float yy1 = fmaxf(A.x, Bv.x), xx1 = fmaxf(A.y, Bv.y);
    float yy2 = fminf(A.z, Bv.z), xx2 = fminf(A.w, Bv.w);
    float inter = fmaxf(yy2 - yy1, 0.f) * fmaxf(xx2 - xx1, 0.f);
    float uni = (ai + aj) - inter;
    return (uni > 0.f) ? inter / uni : 0.f;
}

// ---------------- shared-memory union for the fused kernel ----------------
struct ScanSh {
    uint8_t  cl[PREP];
    uint32_t pr[PREP];
    uint64_t km[NCHUNK];
    uint16_t list[OUT_CNT];
    int      kcs;
};
union SmemU {
    uint32_t h[NBINS];                       // hist: 16 KB
    struct { uint32_t cs[256]; int tbin; } sel;
    uint64_t key[SEGCAP];                    // binsort: 16 KB
    float4   sb[256];                        // edges: 4 KB
    ScanSh   sc;                             // scan: ~34.1 KB (max)
};

// =======================================================================
// Fused cooperative kernel: zero -> hist -> select -> compact -> binsort
//                           -> edges -> scan, separated by grid.sync()
// =======================================================================
__global__ __launch_bounds__(256, 2) void k_all(
        const float* __restrict__ probs, const float* __restrict__ rpn_bbox,
        const float* __restrict__ anchors, float* __restrict__ out,
        char* __restrict__ ws) {
    cg::grid_group grid = cg::this_grid();
    const int bid = blockIdx.x, tid = threadIdx.x;

    uint32_t* hist  = (uint32_t*)(ws + OFF_HIST);
    uint32_t* bcnt  = (uint32_t*)(ws + OFF_BCNT);
    uint32_t* cnt   = (uint32_t*)(ws + OFF_CNT);
    uint32_t* tinfo = (uint32_t*)(ws + OFF_TINFO);
    uint32_t* cum   = (uint32_t*)(ws + OFF_CUM);
    float*    boxes = (float*)(ws + OFF_BOXES);
    uint64_t* candS = (uint64_t*)(ws + OFF_CANDS);
    uint16_t* edges = (uint16_t*)(ws + OFF_EDGES);

    __shared__ SmemU sm;

    // ---- P0: zero counters ----
    {
        uint4* z = (uint4*)ws;
        for (int i = bid * 256 + tid; i < (int)(ZEND / 16); i += NBLK * 256)
            z[i] = make_uint4(0u, 0u, 0u, 0u);
    }
    grid.sync();

    // ---- P1: histogram (64 blocks/batch) ----
    {
        int b = bid >> 6, sub = bid & 63;
        for (int i = tid; i < NBINS; i += 256) sm.h[i] = 0;
        __syncthreads();
        const float4* p4 = (const float4*)(probs + (size_t)b * NA * 2);
        const int total = NA / 2;
        for (int q = sub * 256 + tid; q < total; q += 64 * 256) {
            float4 v = p4[q];
            atomicAdd(&sm.h[score_bin(v.y)], 1u);
            atomicAdd(&sm.h[score_bin(v.w)], 1u);
        }
        __syncthreads();
        uint32_t* gh = hist + b * NBINS;
        for (int i = tid; i < NBINS; i += 256)
            if (sm.h[i]) atomicAdd(&gh[i], sm.h[i]);
    }
    grid.sync();

    // ---- P2: threshold + suffix cum (8 blocks) ----
    if (bid < NBATCH) {
        int b = bid;
        const uint32_t* gh = hist + b * NBINS;
        uint32_t* gc = cum + (size_t)b * (NBINS + 1);
        int t = tid;
        uint32_t loc[16];
        uint32_t s = 0;
        for (int i = 0; i < 16; ++i) { loc[i] = gh[t * 16 + i]; s += loc[i]; }
        sm.sel.cs[t] = s;
        if (t == 0) sm.sel.tbin = 0;
        __syncthreads();
        if (t == 0) {
            uint32_t acc = 0;
            for (int c = 255; c >= 0; --c) { uint32_t v = sm.sel.cs[c]; sm.sel.cs[c] = acc; acc += v; }
        }
        __syncthreads();
        uint32_t acc = sm.sel.cs[t];
        int localT = -1;
        for (int i = 15; i >= 0; --i) {
            int bin = t * 16 + i;
            acc += loc[i];
            gc[bin] = acc;
            if (localT < 0 && acc >= PRE) localT = bin;
        }
        if (t == 255) gc[NBINS] = 0;
        if (localT >= 0) atomicMax(&sm.sel.tbin, localT);
        __syncthreads();
        if (t == 0) tinfo[b] = (uint32_t)sm.sel.tbin;
    }
    grid.sync();

    // ---- P3: compact into bin segments (64 blocks/batch) ----
    {
        int b = bid >> 6, sub = bid & 63;
        int T = (int)tinfo[b];
        const uint32_t* gc = cum + (size_t)b * (NBINS + 1);
        uint32_t* bc = bcnt + (size_t)b * NBINS;
        uint64_t* cs = candS + (size_t)b * CANDCAP;
        const float4* p4 = (const float4*)(probs + (size_t)b * NA * 2);
        const int total = NA / 2;
        for (int q = sub * 256 + tid; q < total; q += 64 * 256) {
            float4 v = p4[q];
            #pragma unroll
            for (int k = 0; k < 2; ++k) {
                float s = k ? v.w : v.y;
                int anchor = 2 * q + k;
                int bin = score_bin(s);
                if (bin >= T) {
                    uint32_t r = atomicAdd(&bc[bin], 1u);
                    uint32_t pos = gc[bin + 1] + r;
                    if (pos < CANDCAP) {
                        uint32_t sb = __float_as_uint(s);
                        cs[pos] = ((uint64_t)(~sb) << 32) | (uint32_t)anchor;
                    }
                }
            }
        }
    }
    grid.sync();

    // ---- P4: per-bin sort + gather + transform (64 bin-slots/batch) ----
    {
        int b = bid & 7;
        int T = (int)tinfo[b];
        const uint32_t* gh = hist + b * NBINS;
        const uint32_t* gc = cum + (size_t)b * (NBINS + 1);
        const uint64_t* cs = candS + (size_t)b * CANDCAP;
        const float4* an4 = (const float4*)(anchors + (size_t)b * NA * 4);
        const float4* bb4 = (const float4*)(rpn_bbox + (size_t)b * NA * 4);
        float4* bx = (float4*)(boxes) + (size_t)b * PREP;
        for (int bin = T + (bid >> 3); bin < NBINS; bin += 64) {
            int n = (int)gh[bin];
            if (n == 0) continue;
            if (n > SEGCAP) n = SEGCAP;
            uint32_t base = gc[bin + 1];
            if (base >= PRE) continue;
            int P = 1; while (P < n) P <<= 1;
            for (int i = tid; i < P; i += 256)
                sm.key[i] = (i < n) ? cs[base + i] : ~0ull;
            __syncthreads();
            for (int k = 2; k <= P; k <<= 1) {
                for (int j = k >> 1; j > 0; j >>= 1) {
                    for (int i = tid; i < P; i += 256) {
                        int ixj = i ^ j;
                        if (ixj > i) {
                            uint64_t a = sm.key[i], c = sm.key[ixj];
                            bool up = ((i & k) == 0);
                            if ((a > c) == up) { sm.key[i] = c; sm.key[ixj] = a; }
                        }
                    }
                    __syncthreads();
                }
            }
            for (int r = tid; r < n; r += 256) {
                uint32_t pos = base + (uint32_t)r;
                if (pos < PRE) {
                    uint32_t aidx = (uint32_t)(sm.key[r] & 0xFFFFFFFFu);
                    float4 a = an4[aidx];
                    float4 d = bb4[aidx];
                    float dy = d.x * 0.1f, dx = d.y * 0.1f, dh = d.z * 0.2f, dw = d.w * 0.2f;
                    float h = a.z - a.x, w = a.w - a.y;
                    float cy = a.x + 0.5f * h;  cy = cy + dy * h;
                    float cx = a.y + 0.5f * w;  cx = cx + dx * w;
                    h = h * expf(dh);
                    w = w * expf(dw);
                    float y1 = cy - 0.5f * h, x1 = cx - 0.5f * w;
                    float y2 = y1 + h, x2 = x1 + w;
                    float4 o;
                    o.x = fminf(fmaxf(y1, 0.f), 1.f);
                    o.y = fminf(fmaxf(x1, 0.f), 1.f);
                    o.z = fminf(fmaxf(y2, 0.f), 1.f);
                    o.w = fminf(fmaxf(x2, 0.f), 1.f);
                    bx[pos] = o;
                }
            }
            __syncthreads();
        }
    }
    grid.sync();

    // ---- P5: overlap edges (624 tile-units over 512 blocks) ----
    {
        for (int u = bid; u < NTPE * NBATCH; u += NBLK) {
            int b = u / NTPE, t = u % NTPE;
            int ti = 0, rem = t;
            while (rem >= NJT - ti) { rem -= NJT - ti; ++ti; }
            int tj = ti + rem;
            const float4* bx = (const float4*)(boxes) + (size_t)b * PREP;
            __syncthreads();
            sm.sb[tid] = bx[ti * 256 + tid];
            __syncthreads();
            int gj = tj * 256 + tid;
            float4 Jb = bx[gj];
            float jy1 = Jb.x, jx1 = Jb.y, jy2 = Jb.z, jx2 = Jb.w;
            float aj = (jy2 - jy1) * (jx2 - jx1);
            float thr = 0.6f * aj;
            bool diag = (ti == tj);
            uint32_t* cb = cnt + (size_t)b * PREP;
            uint16_t* eb = edges + (size_t)b * PREP * ECAP;
            int gibase = ti * 256;
            #pragma unroll 4
            for (int it = 0; it < 256; ++it) {
                float4 I = sm.sb[it];
                float yy1 = fmaxf(jy1, I.x), xx1 = fmaxf(jx1, I.y);
                float yy2 = fminf(jy2, I.z), xx2 = fminf(jx2, I.w);
                float ih = fmaxf(yy2 - yy1, 0.f), iw = fmaxf(xx2 - xx1, 0.f);
                float inter = ih * iw;
                if (inter > thr) {
                    int gi = gibase + it;
                    if (!diag || gi < gj) {
                        float ai = (I.z - I.x) * (I.w - I.y);
                        float uni = (ai + aj) - inter;   // reference op order
                        float iou = inter / uni;
                        if (iou > NMS_THR) {
                            uint32_t slot = atomicAdd(&cb[gj], 1u);
                            if (slot < ECAP) eb[(size_t)gj * ECAP + slot] = (uint16_t)gi;
                        }
                    }
                }
            }
        }
    }
    grid.sync();

    // ---- P6: keep-scan + output (8 blocks) ----
    if (bid < NBATCH) {
        int b = bid;
        const uint32_t* cb = cnt + (size_t)b * PREP;
        const uint32_t* eb32 = (const uint32_t*)(edges + (size_t)b * PREP * ECAP);
        const uint4*    eb128 = (const uint4*)(edges + (size_t)b * PREP * ECAP);
        #pragma unroll 4
        for (int j = tid; j < PREP; j += 256) {
            uint32_t c = cb[j];
            sm.sc.cl[j] = (j < J0) ? (uint8_t)(c > 255u ? 255u : c) : (uint8_t)255;
            sm.sc.pr[j] = eb32[j * 4];
        }
        __syncthreads();
        const float4* bx = (const float4*)(boxes) + (size_t)b * PREP;
        if (tid < 64) {
            int lane = tid;
            int kc = 0;
            for (int c0 = 0; c0 < NCHUNK; ++c0) {
                int base = c0 * 64;
                int j = base + lane;
                bool valid = j < PRE;
                uint64_t word = __ballot(valid);
                int cv = valid ? (int)sm.sc.cl[j] : 0;
                uint32_t prv = sm.sc.pr[j];
                uint4 ev = make_uint4(0u, 0u, 0u, 0u);
                bool manym = (cv >= 3 && cv <= ECAP);
                if (__ballot(manym)) { if (manym) ev = eb128[j]; }
                bool same = false, supB = false;
                bool hard = valid && (cv > ECAP);
                if (valid && cv > 0 && cv <= ECAP) {
                    if (cv <= 2) {
                        int p0 = (int)(prv & 0xFFFFu);
                        int p1 = (int)(prv >> 16);
                        bool s1 = (cv == 2) && (p1 >= base);
                        same = (p0 >= base) || s1;
                        if (!same) {
                            supB = ((sm.sc.km[p0 >> 6] >> (p0 & 63)) & 1ull) != 0ull;
                            if (!supB && cv == 2)
                                supB = ((sm.sc.km[p1 >> 6] >> (p1 & 63)) & 1ull) != 0ull;
                        }
                    } else {
                        int es[8] = { (int)(ev.x & 0xFFFFu), (int)(ev.x >> 16),
                                      (int)(ev.y & 0xFFFFu), (int)(ev.y >> 16),
                                      (int)(ev.z & 0xFFFFu), (int)(ev.z >> 16),
                                      (int)(ev.w & 0xFFFFu), (int)(ev.w >> 16) };
                        #pragma unroll
                        for (int k = 0; k < 8; ++k)
                            if (k < cv) same = same || (es[k] >= base);
                        if (!same) {
                            #pragma unroll
                            for (int k = 0; k < 8; ++k)
                                if (k < cv && !supB)
                                    supB = ((sm.sc.km[es[k] >> 6] >> (es[k] & 63)) & 1ull) != 0ull;
                        }
                    }
                }
                word &= ~__ballot(supB);
                uint64_t fix = __ballot(same || hard);
                while (fix) {
                    int p = __ffsll((unsigned long long)fix) - 1;
                    fix &= fix - 1;
                    int jp = base + p;
                    int cvp = __shfl(cv, p);
                    bool sup = false;
                    if (cvp <= ECAP) {
                        uint32_t prp = (uint32_t)__shfl((int)prv, p);
                        uint32_t evx = (uint32_t)__shfl((int)ev.x, p);
                        uint32_t evy = (uint32_t)__shfl((int)ev.y, p);
                        uint32_t evz = (uint32_t)__shfl((int)ev.z, p);
                        uint32_t evw = (uint32_t)__shfl((int)ev.w, p);
                        int es[8];
                        if (cvp <= 2) {
                            es[0] = (int)(prp & 0xFFFFu); es[1] = (int)(prp >> 16);
                            es[2] = es[3] = es[4] = es[5] = es[6] = es[7] = 0;
                        } else {
                            es[0] = (int)(evx & 0xFFFFu); es[1] = (int)(evx >> 16);
                            es[2] = (int)(evy & 0xFFFFu); es[3] = (int)(evy >> 16);
                            es[4] = (int)(evz & 0xFFFFu); es[5] = (int)(evz >> 16);
                            es[6] = (int)(evw & 0xFFFFu); es[7] = (int)(evw >> 16);
                        }
                        #pragma unroll
                        for (int k = 0; k < 8; ++k) {
                            if (k < cvp && !sup) {
                                int e = es[k];
                                bool kept = (e >= base)
                                    ? (((word >> (e - base)) & 1ull) != 0ull)
                                    : (((sm.sc.km[e >> 6] >> (e & 63)) & 1ull) != 0ull);
                                sup = sup || kept;
                            }
                        }
                    } else {
                        float4 J = bx[jp];
                        bool any = false;
                        for (int t2 = lane; t2 < kc; t2 += 64)
                            if (iou_of(bx[sm.sc.list[t2]], J) > NMS_THR) any = true;
                        if (lane < p && ((word >> lane) & 1ull))
                            if (iou_of(bx[base + lane], J) > NMS_THR) any = true;
                        sup = (__ballot(any) != 0ull);
                    }
                    if (sup) word &= ~(1ull << p);
                }
                sm.sc.km[c0] = word;
                int pos = kc + __popcll(word & ((1ull << lane) - 1ull));
                if (((word >> lane) & 1ull) && pos < OUT_CNT) sm.sc.list[pos] = (uint16_t)j;
                kc += __popcll(word);
                if (kc >= OUT_CNT) { kc = OUT_CNT; break; }
            }
            if (lane == 0) sm.sc.kcs = kc;
        }
        __syncthreads();
        int kc = sm.sc.kcs;
        float4* ob = (float4*)(out) + (size_t)b * OUT_CNT;
        for (int r = tid; r < OUT_CNT; r += 256) {
            float4 o = make_float4(0.f, 0.f, 0.f, 0.f);
            if (r < kc) o = bx[sm.sc.list[r]];
            ob[r] = o;
        }
    }
}

// =======================================================================
// Fallback: round-7 seven-kernel pipeline (used only if cooperative
// launch is rejected; identical semantics)
// =======================================================================
__global__ __launch_bounds__(256) void k_zero(uint4* __restrict__ p) {
    p[blockIdx.x * 256 + threadIdx.x] = make_uint4(0u, 0u, 0u, 0u);
}

__global__ void k_hist(const float* __restrict__ probs, uint32_t* __restrict__ hist) {
    __shared__ uint32_t h[NBINS];
    int b = blockIdx.y;
    for (int i = threadIdx.x; i < NBINS; i += blockDim.x) h[i] = 0;
    __syncthreads();
    const float4* p4 = (const float4*)(probs + (size_t)b * NA * 2);
    const int total = NA / 2;
    const int stride = gridDim.x * blockDim.x;
    for (int q = blockIdx.x * blockDim.x + threadIdx.x; q < total; q += stride) {
        float4 v = p4[q];
        atomicAdd(&h[score_bin(v.y)], 1u);
        atomicAdd(&h[score_bin(v.w)], 1u);
    }
    __syncthreads();
    uint32_t* gh = hist + b * NBINS;
    for (int i = threadIdx.x; i < NBINS; i += blockDim.x)
        if (h[i]) atomicAdd(&gh[i], h[i]);
}

__global__ void k_select(const uint32_t* __restrict__ hist, uint32_t* __restrict__ tinfo,
                         uint32_t* __restrict__ cum) {
    int b = blockIdx.x;
    const uint32_t* gh = hist + b * NBINS;
    uint32_t* gc = cum + (size_t)b * (NBINS + 1);
    __shared__ uint32_t cs[256];
    __shared__ int tbin;
    int t = threadIdx.x;
    uint32_t loc[16];
    uint32_t s = 0;
    for (int i = 0; i < 16; ++i) { loc[i] = gh[t * 16 + i]; s += loc[i]; }
    cs[t] = s;
    if (t == 0) tbin = 0;
    __syncthreads();
    if (t == 0) {
        uint32_t acc = 0;
        for (int c = 255; c >= 0; --c) { uint32_t v = cs[c]; cs[c] = acc; acc += v; }
    }
    __syncthreads();
    uint32_t acc = cs[t];
    int localT = -1;
    for (int i = 15; i >= 0; --i) {
        int bin = t * 16 + i;
        acc += loc[i];
        gc[bin] = acc;
        if (localT < 0 && acc >= PRE) localT = bin;
    }
    if (t == 255) gc[NBINS] = 0;
    if (localT >= 0) atomicMax(&tbin, localT);
    __syncthreads();
    if (t == 0) tinfo[b] = (uint32_t)tbin;
}

__global__ void k_compactD(const float* __restrict__ probs, const uint32_t* __restrict__ tinfo,
                           const uint32_t* __restrict__ cum, uint32_t* __restrict__ bcnt,
                           uint64_t* __restrict__ candS) {
    int b = blockIdx.y;
    int T = (int)tinfo[b];
    const uint32_t* gc = cum + (size_t)b * (NBINS + 1);
    uint32_t* bc = bcnt + (size_t)b * NBINS;
    uint64_t* cs = candS + (size_t)b * CANDCAP;
    const float4* p4 = (const float4*)(probs + (size_t)b * NA * 2);
    const int total = NA / 2;
    const int stride = gridDim.x * blockDim.x;
    for (int q = blockIdx.x * blockDim.x + threadIdx.x; q < total; q += stride) {
        float4 v = p4[q];
        #pragma unroll
        for (int k = 0; k < 2; ++k) {
            float s = k ? v.w : v.y;
            int anchor = 2 * q + k;
            int bin = score_bin(s);
            if (bin >= T) {
                uint32_t r = atomicAdd(&bc[bin], 1u);
                uint32_t pos = gc[bin + 1] + r;
                if (pos < CANDCAP) {
                    uint32_t sb = __float_as_uint(s);
                    cs[pos] = ((uint64_t)(~sb) << 32) | (uint32_t)anchor;
                }
            }
        }
    }
}

__global__ __launch_bounds__(256) void k_binsort(
        const uint64_t* __restrict__ candS, const uint32_t* __restrict__ tinfo,
        const uint32_t* __restrict__ hist, const uint32_t* __restrict__ cum,
        const float* __restrict__ rpn_bbox, const float* __restrict__ anchors,
        float* __restrict__ boxes) {
    __shared__ uint64_t key[SEGCAP];
    int b = blockIdx.y;
    int T = (int)tinfo[b];
    const uint32_t* gh = hist + b * NBINS;
    const uint32_t* gc = cum + (size_t)b * (NBINS + 1);
    const uint64_t* cs = candS + (size_t)b * CANDCAP;
    const float4* an4 = (const float4*)(anchors + (size_t)b * NA * 4);
    const float4* bb4 = (const float4*)(rpn_bbox + (size_t)b * NA * 4);
    float4* bx = (float4*)(boxes) + (size_t)b * PREP;
    for (int bin = T + blockIdx.x; bin < NBINS; bin += gridDim.x) {
        int n = (int)gh[bin];
        if (n == 0) continue;
        if (n > SEGCAP) n = SEGCAP;
        uint32_t base = gc[bin + 1];
        if (base >= PRE) continue;
        int P = 1; while (P < n) P <<= 1;
        for (int i = threadIdx.x; i < P; i += 256)
            key[i] = (i < n) ? cs[base + i] : ~0ull;
        __syncthreads();
        for (int k = 2; k <= P; k <<= 1) {
            for (int j = k >> 1; j > 0; j >>= 1) {
                for (int i = threadIdx.x; i < P; i += 256) {
                    int ixj = i ^ j;
                    if (ixj > i) {
                        uint64_t a = key[i], c = key[ixj];
                        bool up = ((i & k) == 0);
                        if ((a > c) == up) { key[i] = c; key[ixj] = a; }
                    }
                }
                __syncthreads();
            }
        }
        for (int r = threadIdx.x; r < n; r += 256) {
            uint32_t pos = base + (uint32_t)r;
            if (pos < PRE) {
                uint32_t aidx = (uint32_t)(key[r] & 0xFFFFFFFFu);
                float4 a = an4[aidx];
                float4 d = bb4[aidx];
                float dy = d.x * 0.1f, dx = d.y * 0.1f, dh = d.z * 0.2f, dw = d.w * 0.2f;
                float h = a.z - a.x, w = a.w - a.y;
                float cy = a.x + 0.5f * h;  cy = cy + dy * h;
                float cx = a.y + 0.5f * w;  cx = cx + dx * w;
                h = h * expf(dh);
                w = w * expf(dw);
                float y1 = cy - 0.5f * h, x1 = cx - 0.5f * w;
                float y2 = y1 + h, x2 = x1 + w;
                float4 o;
                o.x = fminf(fmaxf(y1, 0.f), 1.f);
                o.y = fminf(fmaxf(x1, 0.f), 1.f);
                o.z = fminf(fmaxf(y2, 0.f), 1.f);
                o.w = fminf(fmaxf(x2, 0.f), 1.f);
                bx[pos] = o;
            }
        }
        __syncthreads();
    }
}

__global__ __launch_bounds__(256) void k_edges(const float* __restrict__ boxes,
                                               uint32_t* __restrict__ cnt,
                                               uint16_t* __restrict__ edges) {
    int b = blockIdx.y;
    int t = blockIdx.x;
    int ti = 0, rem = t;
    while (rem >= NJT - ti) { rem -= NJT - ti; ++ti; }
    int tj = ti + rem;
    __shared__ float4 sb[256];
    const float4* bx = (const float4*)(boxes) + (size_t)b * PREP;
    sb[threadIdx.x] = bx[ti * 256 + threadIdx.x];
    __syncthreads();
    int gj = tj * 256 + threadIdx.x;
    float4 Jb = bx[gj];
    float jy1 = Jb.x, jx1 = Jb.y, jy2 = Jb.z, jx2 = Jb.w;
    float aj = (jy2 - jy1) * (jx2 - jx1);
    float thr = 0.6f * aj;
    bool diag = (ti == tj);
    uint32_t* cb = cnt + (size_t)b * PREP;
    uint16_t* eb = edges + (size_t)b * PREP * ECAP;
    int gibase = ti * 256;
    #pragma unroll 4
    for (int it = 0; it < 256; ++it) {
        float4 I = sb[it];
        float yy1 = fmaxf(jy1, I.x), xx1 = fmaxf(jx1, I.y);
        float yy2 = fminf(jy2, I.z), xx2 = fminf(jx2, I.w);
        float ih = fmaxf(yy2 - yy1, 0.f), iw = fmaxf(xx2 - xx1, 0.f);
        float inter = ih * iw;
        if (inter > thr) {
            int gi = gibase + it;
            if (!diag || gi < gj) {
                float ai = (I.z - I.x) * (I.w - I.y);
                float uni = (ai + aj) - inter;
                float iou = inter / uni;
                if (iou > NMS_THR) {
                    uint32_t slot = atomicAdd(&cb[gj], 1u);
                    if (slot < ECAP) eb[(size_t)gj * ECAP + slot] = (uint16_t)gi;
                }
            }
        }
    }
}

__global__ __launch_bounds__(256) void k_scan(const float* __restrict__ boxes,
                                              const uint32_t* __restrict__ cnt,
                                              const uint16_t* __restrict__ edges,
                                              float* __restrict__ out) {
    int b = blockIdx.x;
    __shared__ uint8_t  cl[PREP];
    __shared__ uint32_t pr[PREP];
    __shared__ uint64_t km[NCHUNK];
    __shared__ uint16_t list[OUT_CNT];
    __shared__ int kcs;
    int tid = threadIdx.x;
    const uint32_t* cb = cnt + (size_t)b * PREP;
    const uint32_t* eb32 = (const uint32_t*)(edges + (size_t)b * PREP * ECAP);
    const uint4*    eb128 = (const uint4*)(edges + (size_t)b * PREP * ECAP);
    #pragma unroll 4
    for (int j = tid; j < PREP; j += 256) {
        uint32_t c = cb[j];
        cl[j] = (j < J0) ? (uint8_t)(c > 255u ? 255u : c) : (uint8_t)255;
        pr[j] = eb32[j * 4];
    }
    __syncthreads();
    const float4* bx = (const float4*)(boxes) + (size_t)b * PREP;
    if (tid < 64) {
        int lane = tid;
        int kc = 0;
        for (int c0 = 0; c0 < NCHUNK; ++c0) {
            int base = c0 * 64;
            int j = base + lane;
            bool valid = j < PRE;
            uint64_t word = __ballot(valid);
            int cv = valid ? (int)cl[j] : 0;
            uint32_t prv = pr[j];
            uint4 ev = make_uint4(0u, 0u, 0u, 0u);
            bool manym = (cv >= 3 && cv <= ECAP);
            if (__ballot(manym)) { if (manym) ev = eb128[j]; }
            bool same = false, supB = false;
            bool hard = valid && (cv > ECAP);
            if (valid && cv > 0 && cv <= ECAP) {
                if (cv <= 2) {
                    int p0 = (int)(prv & 0xFFFFu);
                    int p1 = (int)(prv >> 16);
                    bool s1 = (cv == 2) && (p1 >= base);
                    same = (p0 >= base) || s1;
                    if (!same) {
                        supB = ((km[p0 >> 6] >> (p0 & 63)) & 1ull) != 0ull;
                        if (!supB && cv == 2)
                            supB = ((km[p1 >> 6] >> (p1 & 63)) & 1ull) != 0ull;
                    }
                } else {
                    int es[8] = { (int)(ev.x & 0xFFFFu), (int)(ev.x >> 16),
                                  (int)(ev.y & 0xFFFFu), (int)(ev.y >> 16),
                                  (int)(ev.z & 0xFFFFu), (int)(ev.z >> 16),
                                  (int)(ev.w & 0xFFFFu), (int)(ev.w >> 16) };
                    #pragma unroll
                    for (int k = 0; k < 8; ++k)
                        if (k < cv) same = same || (es[k] >= base);
                    if (!same) {
                        #pragma unroll
                        for (int k = 0; k < 8; ++k)
                            if (k < cv && !supB)
                                supB = ((km[es[k] >> 6] >> (es[k] & 63)) & 1ull) != 0ull;
                    }
                }
            }
            word &= ~__ballot(supB);
            uint64_t fix = __ballot(same || hard);
            while (fix) {
                int p = __ffsll((unsigned long long)fix) - 1;
                fix &= fix - 1;
                int jp = base + p;
                int cvp = __shfl(cv, p);
                bool sup = false;
                if (cvp <= ECAP) {
                    uint32_t prp = (uint32_t)__shfl((int)prv, p);
                    uint32_t evx = (uint32_t)__shfl((int)ev.x, p);
                    uint32_t evy = (uint32_t)__shfl((int)ev.y, p);
                    uint32_t evz = (uint32_t)__shfl((int)ev.z, p);
                    uint32_t evw = (uint32_t)__shfl((int)ev.w, p);
                    int es[8];
                    if (cvp <= 2) {
                        es[0] = (int)(prp & 0xFFFFu); es[1] = (int)(prp >> 16);
                        es[2] = es[3] = es[4] = es[5] = es[6] = es[7] = 0;
                    } else {
                        es[0] = (int)(evx & 0xFFFFu); es[1] = (int)(evx >> 16);
                        es[2] = (int)(evy & 0xFFFFu); es[3] = (int)(evy >> 16);
                        es[4] = (int)(evz & 0xFFFFu); es[5] = (int)(evz >> 16);
                        es[6] = (int)(evw & 0xFFFFu); es[7] = (int)(evw >> 16);
                    }
                    #pragma unroll
                    for (int k = 0; k < 8; ++k) {
                        if (k < cvp && !sup) {
                            int e = es[k];
                            bool kept = (e >= base)
                                ? (((word >> (e - base)) & 1ull) != 0ull)
                                : (((km[e >> 6] >> (e & 63)) & 1ull) != 0ull);
                            sup = sup || kept;
                        }
                    }
                } else {
                    float4 J = bx[jp];
                    bool any = false;
                    for (int t2 = lane; t2 < kc; t2 += 64)
                        if (iou_of(bx[list[t2]], J) > NMS_THR) any = true;
                    if (lane < p && ((word >> lane) & 1ull))
                        if (iou_of(bx[base + lane], J) > NMS_THR) any = true;
                    sup = (__ballot(any) != 0ull);
                }
                if (sup) word &= ~(1ull << p);
            }
            km[c0] = word;
            int pos = kc + __popcll(word & ((1ull << lane) - 1ull));
            if (((word >> lane) & 1ull) && pos < OUT_CNT) list[pos] = (uint16_t)j;
            kc += __popcll(word);
            if (kc >= OUT_CNT) { kc = OUT_CNT; break; }
        }
        if (lane == 0) kcs = kc;
    }
    __syncthreads();
    int kc = kcs;
    float4* ob = (float4*)(out) + (size_t)b * OUT_CNT;
    for (int r = tid; r < OUT_CNT; r += 256) {
        float4 o = make_float4(0.f, 0.f, 0.f, 0.f);
        if (r < kc) o = bx[list[r]];
        ob[r] = o;
    }
}

extern "C" void kernel_launch(void* const* d_in, const int* in_sizes, int n_in,
                              void* d_out, int out_size, void* d_ws, size_t ws_size,
                              hipStream_t stream) {
    const float* probs   = (const float*)d_in[0];
    const float* rpnbbox = (const float*)d_in[1];
    const float* anchors = (const float*)d_in[2];
    float* out = (float*)d_out;
    char* ws = (char*)d_ws;

    void* kargs[] = { (void*)&probs, (void*)&rpnbbox, (void*)&anchors, (void*)&out, (void*)&ws };
    hipError_t err = hipLaunchCooperativeKernel(reinterpret_cast<void*>(k_all),
                                                dim3(NBLK), dim3(256), kargs, 0, stream);
    if (err == hipSuccess) return;

    // deterministic fallback: round-7 pipeline
    uint32_t* hist   = (uint32_t*)(ws + OFF_HIST);
    uint32_t* bcnt   = (uint32_t*)(ws + OFF_BCNT);
    uint32_t* cnt    = (uint32_t*)(ws + OFF_CNT);
    uint32_t* tinfo  = (uint32_t*)(ws + OFF_TINFO);
    uint32_t* cum    = (uint32_t*)(ws + OFF_CUM);
    float*    boxes  = (float*)(ws + OFF_BOXES);
    uint64_t* candS  = (uint64_t*)(ws + OFF_CANDS);
    uint16_t* edges  = (uint16_t*)(ws + OFF_EDGES);

    k_zero<<<NZB, 256, 0, stream>>>((uint4*)ws);
    k_hist<<<dim3(128, NBATCH), 256, 0, stream>>>(probs, hist);
    k_select<<<NBATCH, 256, 0, stream>>>(hist, tinfo, cum);
    k_compactD<<<dim3(128, NBATCH), 256, 0, stream>>>(probs, tinfo, cum, bcnt, candS);
    k_binsort<<<dim3(128, NBATCH), 256, 0, stream>>>(candS, tinfo, hist, cum, rpnbbox, anchors, boxes);
    k_edges<<<dim3(NTPE, NBATCH), 256, 0, stream>>>(boxes, cnt, edges);
    k_scan<<<NBATCH, 256, 0, stream>>>(boxes, cnt, edges, out);
}

// Round 9
// 132.157 us; speedup vs baseline: 3.2708x; 3.2708x over previous
//
#include <hip/hip_runtime.h>
#include <stdint.h>

#define NBATCH   8
#define NA       261888
#define PRE      6000
#define PREP     6016
#define NCHUNK   94
#define OUT_CNT  2000
#define NMS_THR  0.7f
#define NBINS    4096
#define CANDCAP  16384
#define LCAP     512
#define ECAP     8
#define SEGCAP   2048
#define T0S      3936     // static pre-threshold bin: E[cum above]=10230 >> 6000 (40 sigma)
#define J0       3072     // edges computed only for j < J0; scan falls back past it
#define NJT      12       // J0 / 256
#define NTPE     78       // NJT*(NJT+1)/2 tile-pairs
#define NSUB     128      // pass1 blocks per batch

// workspace layout (bytes) — ws_size ~268 MB, we use ~4 MB
#define OFF_HIST     0ull                      // 8*4096*4 = 131072
#define OFF_GCNT     131072ull                 // 32
#define OFF_DONE     131104ull                 // 32
#define ZEND         131136ull                 // zeroed each call (8196 uint4)
#define NZ4          8196
#define OFF_CUM      131136ull                 // 8*4097*4 = 131104 -> 262240
#define OFF_TINFO    262240ull                 // 32 -> 262272
#define OFF_CANDU    262272ull                 // 8*16384*8 = 1048576 -> 1310848
#define OFF_CANDS    1310848ull                // 1048576 -> 2359424
#define OFF_BOXES    2359424ull                // 8*6016*16 = 770048 -> 3129472
#define OFF_CNT      3129472ull                // 8*6016*4 = 192512 -> 3321984 (12032 uint4)
#define OFF_EDGES    3321984ull                // 8*6016*8*2 = 770048 -> 4092032

__device__ __forceinline__ int score_bin(float s) {
    int b = (int)(s * 4096.0f);          // *4096 exact (pow2) -> monotone
    return min(max(b, 0), NBINS - 1);
}

__device__ __forceinline__ float iou_of(float4 A, float4 Bv) {
    float ai = (A.z - A.x) * (A.w - A.y);
    float aj = (Bv.z - Bv.x) * (Bv.w - Bv.y);
    float yy1 = fmaxf(A.x, Bv.x), xx1 = fmaxf(A.y, Bv.y);
    float yy2 = fminf(A.z, Bv.z), xx2 = fminf(A.w, Bv.w);
    float inter = fmaxf(yy2 - yy1, 0.f) * fmaxf(xx2 - xx1, 0.f);
    float uni = (ai + aj) - inter;
    return (uni > 0.f) ? inter / uni : 0.f;
}

// ---------------- K0: zero hist + counters ----------------
__global__ __launch_bounds__(256) void k_zero(uint4* __restrict__ p) {
    int i = blockIdx.x * 256 + threadIdx.x;
    if (i < NZ4) p[i] = make_uint4(0u, 0u, 0u, 0u);
}

// ---------------- K1: single-pass hist + static-threshold compact + last-block select ----
__global__ __launch_bounds__(256) void k_pass1(
        const float* __restrict__ probs, uint32_t* __restrict__ hist,
        uint32_t* __restrict__ gcount, uint32_t* __restrict__ done,
        uint64_t* __restrict__ candU, uint32_t* __restrict__ tinfo,
        uint32_t* __restrict__ cum) {
    __shared__ uint32_t h[NBINS];            // 16 KB
    __shared__ uint64_t lkey[LCAP];          // 4 KB
    __shared__ uint32_t lcnt, lbase, rank;
    __shared__ int tbin;
    int b = blockIdx.y, sub = blockIdx.x, tid = threadIdx.x;
    for (int i = tid; i < NBINS; i += 256) h[i] = 0;
    if (tid == 0) lcnt = 0;
    __syncthreads();
    const float4* p4 = (const float4*)(probs + (size_t)b * NA * 2);
    const int total = NA / 2;
    for (int q = sub * 256 + tid; q < total; q += NSUB * 256) {
        float4 v = p4[q];
        #pragma unroll
        for (int k = 0; k < 2; ++k) {
            float s = k ? v.w : v.y;
            int bin = score_bin(s);
            atomicAdd(&h[bin], 1u);
            if (bin >= T0S) {
                uint32_t p = atomicAdd(&lcnt, 1u);
                if (p < LCAP) {
                    uint32_t sb = __float_as_uint(s);
                    lkey[p] = ((uint64_t)(~sb) << 32) | (uint32_t)(2 * q + k);
                }
            }
        }
    }
    __syncthreads();
    uint32_t* gh = hist + b * NBINS;
    for (int i = tid; i < NBINS; i += 256)
        if (h[i]) atomicAdd(&gh[i], h[i]);
    uint32_t n = min(lcnt, (uint32_t)LCAP);
    if (tid == 0) lbase = atomicAdd(&gcount[b], n);
    __syncthreads();
    uint64_t* cb = candU + (size_t)b * CANDCAP;
    for (uint32_t i = tid; i < n; i += 256) {
        uint32_t pos = lbase + i;
        if (pos < CANDCAP) cb[pos] = lkey[i];
    }
    __syncthreads();
    if (tid == 0) rank = atomicAdd(&done[b], 1u);   // device-scope; hist atomics already coherent
    __syncthreads();
    if (rank != NSUB - 1) return;

    // ---- last block of this batch: exact threshold + suffix cum (atomic reads of hist) ----
    uint32_t* gc = cum + (size_t)b * (NBINS + 1);
    uint32_t* cs = h;                        // reuse LDS
    int t = tid;
    uint32_t loc[16];
    uint32_t s = 0;
    for (int i = 0; i < 16; ++i) { loc[i] = atomicAdd(&gh[t * 16 + i], 0u); s += loc[i]; }
    cs[t] = s;
    if (t == 0) tbin = 0;
    __syncthreads();
    if (t == 0) {
        uint32_t acc = 0;
        for (int c = 255; c >= 0; --c) { uint32_t v = cs[c]; cs[c] = acc; acc += v; }
    }
    __syncthreads();
    uint32_t acc = cs[t];
    int localT = -1;
    for (int i = 15; i >= 0; --i) {
        int bin = t * 16 + i;
        acc += loc[i];
        gc[bin] = acc;
        if (localT < 0 && acc >= PRE) localT = bin;
    }
    if (t == 255) gc[NBINS] = 0;
    if (localT >= 0) atomicMax(&tbin, localT);
    __syncthreads();
    if (t == 0) tinfo[b] = (uint32_t)tbin;
}

// ---------------- K2: scatter candidates into bin segments (1 block/batch) ----------------
__global__ __launch_bounds__(1024) void k_binscatter(
        const float* __restrict__ probs,
        uint64_t* __restrict__ candU, uint32_t* __restrict__ gcount,
        const uint32_t* __restrict__ tinfo, const uint32_t* __restrict__ cum,
        uint64_t* __restrict__ candS) {
    int b = blockIdx.x, tid = threadIdx.x;
    __shared__ uint32_t bc[NBINS];           // 16 KB
    __shared__ uint32_t gcum[NBINS + 1];     // 16 KB
    const uint32_t* gc = cum + (size_t)b * (NBINS + 1);
    for (int i = tid; i < NBINS; i += 1024) bc[i] = 0;
    for (int i = tid; i < NBINS + 1; i += 1024) gcum[i] = gc[i];
    __syncthreads();
    uint64_t* cu = candU + (size_t)b * CANDCAP;
    // never-taken exact fallback: static T0 missed part of the top-PRE set
    if (gcum[T0S] < PRE) {
        int T = (int)tinfo[b];
        const float4* p4 = (const float4*)(probs + (size_t)b * NA * 2);
        for (int q = tid; q < NA / 2; q += 1024) {
            float4 v = p4[q];
            #pragma unroll
            for (int k = 0; k < 2; ++k) {
                float s = k ? v.w : v.y;
                int bin = score_bin(s);
                if (bin >= T && bin < T0S) {
                    uint32_t pos = atomicAdd(&gcount[b], 1u);
                    if (pos < CANDCAP) {
                        uint32_t sb = __float_as_uint(s);
                        cu[pos] = ((uint64_t)(~sb) << 32) | (uint32_t)(2 * q + k);
                    }
                }
            }
        }
        __threadfence_block();
        __syncthreads();
    }
    uint32_t C = min(gcount[b], (uint32_t)CANDCAP);
    uint64_t* cs = candS + (size_t)b * CANDCAP;
    for (uint32_t i = tid; i < C; i += 1024) {
        uint64_t k = cu[i];
        float s = __uint_as_float(~(uint32_t)(k >> 32));
        int bin = score_bin(s);
        uint32_t r = atomicAdd(&bc[bin], 1u);
        uint32_t pos = gcum[bin + 1] + r;
        if (pos < CANDCAP) cs[pos] = k;
    }
}

// ---------------- K3: per-bin sort + gather + transform (also zeros cnt) ----------------
__global__ __launch_bounds__(256) void k_binsort(
        const uint64_t* __restrict__ candS, const uint32_t* __restrict__ tinfo,
        const uint32_t* __restrict__ hist, const uint32_t* __restrict__ cum,
        const float* __restrict__ rpn_bbox, const float* __restrict__ anchors,
        float* __restrict__ boxes, uint4* __restrict__ cntz) {
    __shared__ uint64_t key[SEGCAP];
    int tid = threadIdx.x;
    {   // zero cnt region (consumed by the LATER k_edges — no barrier needed)
        int zi = (blockIdx.y * gridDim.x + blockIdx.x) * 256 + tid;
        if (zi < 12032) cntz[zi] = make_uint4(0u, 0u, 0u, 0u);
    }
    int b = blockIdx.y;
    int T = (int)tinfo[b];
    const uint32_t* gh = hist + b * NBINS;
    const uint32_t* gc = cum + (size_t)b * (NBINS + 1);
    const uint64_t* cs = candS + (size_t)b * CANDCAP;
    const float4* an4 = (const float4*)(anchors + (size_t)b * NA * 4);
    const float4* bb4 = (const float4*)(rpn_bbox + (size_t)b * NA * 4);
    float4* bx = (float4*)(boxes) + (size_t)b * PREP;

    for (int bin = T + blockIdx.x; bin < NBINS; bin += gridDim.x) {
        int n = (int)gh[bin];
        if (n == 0) continue;
        if (n > SEGCAP) n = SEGCAP;
        uint32_t base = gc[bin + 1];
        if (base >= PRE) continue;
        int P = 1; while (P < n) P <<= 1;
        for (int i = tid; i < P; i += 256)
            key[i] = (i < n) ? cs[base + i] : ~0ull;
        __syncthreads();
        for (int k = 2; k <= P; k <<= 1) {
            for (int j = k >> 1; j > 0; j >>= 1) {
                for (int i = tid; i < P; i += 256) {
                    int ixj = i ^ j;
                    if (ixj > i) {
                        uint64_t a = key[i], c = key[ixj];
                        bool up = ((i & k) == 0);
                        if ((a > c) == up) { key[i] = c; key[ixj] = a; }
                    }
                }
                __syncthreads();
            }
        }
        for (int r = tid; r < n; r += 256) {
            uint32_t pos = base + (uint32_t)r;
            if (pos < PRE) {
                uint32_t aidx = (uint32_t)(key[r] & 0xFFFFFFFFu);
                float4 a = an4[aidx];
                float4 d = bb4[aidx];
                float dy = d.x * 0.1f, dx = d.y * 0.1f, dh = d.z * 0.2f, dw = d.w * 0.2f;
                float h = a.z - a.x, w = a.w - a.y;
                float cy = a.x + 0.5f * h;  cy = cy + dy * h;
                float cx = a.y + 0.5f * w;  cx = cx + dx * w;
                h = h * expf(dh);
                w = w * expf(dw);
                float y1 = cy - 0.5f * h, x1 = cx - 0.5f * w;
                float y2 = y1 + h, x2 = x1 + w;
                float4 o;
                o.x = fminf(fmaxf(y1, 0.f), 1.f);
                o.y = fminf(fmaxf(x1, 0.f), 1.f);
                o.z = fminf(fmaxf(y2, 0.f), 1.f);
                o.w = fminf(fmaxf(x2, 0.f), 1.f);
                bx[pos] = o;
            }
        }
        __syncthreads();
    }
}

// ---------------- K4: overlap edges — 624 blocks, lean inner loop ----------------
__global__ __launch_bounds__(256) void k_edges(const float* __restrict__ boxes,
                                               uint32_t* __restrict__ cnt,
                                               uint16_t* __restrict__ edges) {
    int b = blockIdx.y;
    int t = blockIdx.x;
    int ti = 0, rem = t;
    while (rem >= NJT - ti) { rem -= NJT - ti; ++ti; }
    int tj = ti + rem;                       // ti <= tj < NJT
    __shared__ float4 sb[256];
    const float4* bx = (const float4*)(boxes) + (size_t)b * PREP;
    sb[threadIdx.x] = bx[ti * 256 + threadIdx.x];
    __syncthreads();
    int gj = tj * 256 + threadIdx.x;
    float4 Jb = bx[gj];
    float jy1 = Jb.x, jx1 = Jb.y, jy2 = Jb.z, jx2 = Jb.w;
    float aj = (jy2 - jy1) * (jx2 - jx1);
    float thr = 0.6f * aj;
    bool diag = (ti == tj);
    uint32_t* cb = cnt + (size_t)b * PREP;
    uint16_t* eb = edges + (size_t)b * PREP * ECAP;
    int gibase = ti * 256;
    #pragma unroll 4
    for (int it = 0; it < 256; ++it) {
        float4 I = sb[it];                   // broadcast, conflict-free
        float yy1 = fmaxf(jy1, I.x), xx1 = fmaxf(jx1, I.y);
        float yy2 = fminf(jy2, I.z), xx2 = fminf(jx2, I.w);
        float ih = fmaxf(yy2 - yy1, 0.f), iw = fmaxf(xx2 - xx1, 0.f);
        float inter = ih * iw;
        if (inter > thr) {                   // rare path
            int gi = gibase + it;
            if (!diag || gi < gj) {
                float ai = (I.z - I.x) * (I.w - I.y);
                float uni = (ai + aj) - inter;   // reference op order
                float iou = inter / uni;
                if (iou > NMS_THR) {
                    uint32_t slot = atomicAdd(&cb[gj], 1u);
                    if (slot < ECAP) eb[(size_t)gj * ECAP + slot] = (uint16_t)gi;
                }
            }
        }
    }
}

// ---------------- K5: keep-scan, lane-parallel resolution ----------------
__global__ __launch_bounds__(256) void k_scan(const float* __restrict__ boxes,
                                              const uint32_t* __restrict__ cnt,
                                              const uint16_t* __restrict__ edges,
                                              float* __restrict__ out) {
    int b = blockIdx.x;
    __shared__ uint8_t  cl[PREP];
    __shared__ uint32_t pr[PREP];
    __shared__ uint64_t km[NCHUNK];
    __shared__ uint16_t list[OUT_CNT];
    __shared__ int kcs;
    int tid = threadIdx.x;
    const uint32_t* cb = cnt + (size_t)b * PREP;
    const uint32_t* eb32 = (const uint32_t*)(edges + (size_t)b * PREP * ECAP);
    const uint4*    eb128 = (const uint4*)(edges + (size_t)b * PREP * ECAP);
    #pragma unroll 4
    for (int j = tid; j < PREP; j += 256) {
        uint32_t c = cb[j];
        cl[j] = (j < J0) ? (uint8_t)(c > 255u ? 255u : c) : (uint8_t)255;  // 255 = unknown
        pr[j] = eb32[j * 4];   // slots 0,1
    }
    __syncthreads();
    const float4* bx = (const float4*)(boxes) + (size_t)b * PREP;
    if (tid < 64) {
        int lane = tid;
        int kc = 0;
        for (int c0 = 0; c0 < NCHUNK; ++c0) {
            int base = c0 * 64;
            int j = base + lane;
            bool valid = j < PRE;
            uint64_t word = __ballot(valid);
            int cv = valid ? (int)cl[j] : 0;
            uint32_t prv = pr[j];
            uint4 ev = make_uint4(0u, 0u, 0u, 0u);
            bool manym = (cv >= 3 && cv <= ECAP);
            if (__ballot(manym)) { if (manym) ev = eb128[j]; }
            bool same = false, supB = false;
            bool hard = valid && (cv > ECAP);
            if (valid && cv > 0 && cv <= ECAP) {
                if (cv <= 2) {
                    int p0 = (int)(prv & 0xFFFFu);
                    int p1 = (int)(prv >> 16);
                    bool s1 = (cv == 2) && (p1 >= base);
                    same = (p0 >= base) || s1;
                    if (!same) {
                        supB = ((km[p0 >> 6] >> (p0 & 63)) & 1ull) != 0ull;
                        if (!supB && cv == 2)
                            supB = ((km[p1 >> 6] >> (p1 & 63)) & 1ull) != 0ull;
                    }
                } else {
                    int es[8] = { (int)(ev.x & 0xFFFFu), (int)(ev.x >> 16),
                                  (int)(ev.y & 0xFFFFu), (int)(ev.y >> 16),
                                  (int)(ev.z & 0xFFFFu), (int)(ev.z >> 16),
                                  (int)(ev.w & 0xFFFFu), (int)(ev.w >> 16) };
                    #pragma unroll
                    for (int k = 0; k < 8; ++k)
                        if (k < cv) same = same || (es[k] >= base);
                    if (!same) {
                        #pragma unroll
                        for (int k = 0; k < 8; ++k)
                            if (k < cv && !supB)
                                supB = ((km[es[k] >> 6] >> (es[k] & 63)) & 1ull) != 0ull;
                    }
                }
            }
            word &= ~__ballot(supB);
            uint64_t fix = __ballot(same || hard);
            while (fix) {
                int p = __ffsll((unsigned long long)fix) - 1;
                fix &= fix - 1;
                int jp = base + p;
                int cvp = __shfl(cv, p);
                bool sup = false;
                if (cvp <= ECAP) {
                    uint32_t prp = (uint32_t)__shfl((int)prv, p);
                    uint32_t evx = (uint32_t)__shfl((int)ev.x, p);
                    uint32_t evy = (uint32_t)__shfl((int)ev.y, p);
                    uint32_t evz = (uint32_t)__shfl((int)ev.z, p);
                    uint32_t evw = (uint32_t)__shfl((int)ev.w, p);
                    int es[8];
                    if (cvp <= 2) {
                        es[0] = (int)(prp & 0xFFFFu); es[1] = (int)(prp >> 16);
                        es[2] = es[3] = es[4] = es[5] = es[6] = es[7] = 0;
                    } else {
                        es[0] = (int)(evx & 0xFFFFu); es[1] = (int)(evx >> 16);
                        es[2] = (int)(evy & 0xFFFFu); es[3] = (int)(evy >> 16);
                        es[4] = (int)(evz & 0xFFFFu); es[5] = (int)(evz >> 16);
                        es[6] = (int)(evw & 0xFFFFu); es[7] = (int)(evw >> 16);
                    }
                    #pragma unroll
                    for (int k = 0; k < 8; ++k) {
                        if (k < cvp && !sup) {
                            int e = es[k];
                            bool kept = (e >= base)
                                ? (((word >> (e - base)) & 1ull) != 0ull)
                                : (((km[e >> 6] >> (e & 63)) & 1ull) != 0ull);
                            sup = sup || kept;
                        }
                    }
                } else {
                    float4 J = bx[jp];
                    bool any = false;
                    for (int t2 = lane; t2 < kc; t2 += 64)
                        if (iou_of(bx[list[t2]], J) > NMS_THR) any = true;
                    if (lane < p && ((word >> lane) & 1ull))
                        if (iou_of(bx[base + lane], J) > NMS_THR) any = true;
                    sup = (__ballot(any) != 0ull);
                }
                if (sup) word &= ~(1ull << p);
            }
            km[c0] = word;
            int pos = kc + __popcll(word & ((1ull << lane) - 1ull));
            if (((word >> lane) & 1ull) && pos < OUT_CNT) list[pos] = (uint16_t)j;
            kc += __popcll(word);
            if (kc >= OUT_CNT) { kc = OUT_CNT; break; }
        }
        if (lane == 0) kcs = kc;
    }
    __syncthreads();
    int kc = kcs;
    float4* ob = (float4*)(out) + (size_t)b * OUT_CNT;
    for (int r = tid; r < OUT_CNT; r += 256) {
        float4 o = make_float4(0.f, 0.f, 0.f, 0.f);
        if (r < kc) o = bx[list[r]];
        ob[r] = o;
    }
}

extern "C" void kernel_launch(void* const* d_in, const int* in_sizes, int n_in,
                              void* d_out, int out_size, void* d_ws, size_t ws_size,
                              hipStream_t stream) {
    const float* probs   = (const float*)d_in[0];
    const float* rpnbbox = (const float*)d_in[1];
    const float* anchors = (const float*)d_in[2];
    float* out = (float*)d_out;
    char* ws = (char*)d_ws;

    uint32_t* hist   = (uint32_t*)(ws + OFF_HIST);
    uint32_t* gcount = (uint32_t*)(ws + OFF_GCNT);
    uint32_t* done   = (uint32_t*)(ws + OFF_DONE);
    uint32_t* cum    = (uint32_t*)(ws + OFF_CUM);
    uint32_t* tinfo  = (uint32_t*)(ws + OFF_TINFO);
    uint64_t* candU  = (uint64_t*)(ws + OFF_CANDU);
    uint64_t* candS  = (uint64_t*)(ws + OFF_CANDS);
    float*    boxes  = (float*)(ws + OFF_BOXES);
    uint32_t* cnt    = (uint32_t*)(ws + OFF_CNT);
    uint16_t* edges  = (uint16_t*)(ws + OFF_EDGES);

    k_zero<<<33, 256, 0, stream>>>((uint4*)ws);
    k_pass1<<<dim3(NSUB, NBATCH), 256, 0, stream>>>(probs, hist, gcount, done, candU, tinfo, cum);
    k_binscatter<<<NBATCH, 1024, 0, stream>>>(probs, candU, gcount, tinfo, cum, candS);
    k_binsort<<<dim3(128, NBATCH), 256, 0, stream>>>(candS, tinfo, hist, cum, rpnbbox, anchors,
                                                     boxes, (uint4*)(ws + OFF_CNT));
    k_edges<<<dim3(NTPE, NBATCH), 256, 0, stream>>>(boxes, cnt, edges);
    k_scan<<<NBATCH, 256, 0, stream>>>(boxes, cnt, edges, out);
}

// Round 10
// 104.826 us; speedup vs baseline: 4.1236x; 1.2607x over previous
//
#include <hip/hip_runtime.h>
#include <stdint.h>

#define NBATCH   8
#define NA       261888
#define PRE      6000
#define PREP     6016
#define NCHUNK   94
#define OUT_CNT  2000
#define NMS_THR  0.7f
#define NBINS    4096
#define NHB      160      // histogrammed bins: [T0S, 4096)
#define T0S      3936     // static pre-threshold bin: E[cands]=10230 >> 6000
#define NSUB     64       // pass1 blocks per batch
#define LCAP     512      // per-block candidate segment (E=160, 28 sigma headroom)
#define CANDCAP  16384
#define ECAP     8
#define SEGCAP   2048
#define J0       3072     // edges computed only for j < J0; scan falls back past it
#define NJT      12       // J0 / 256
#define NTPE     78       // NJT*(NJT+1)/2 tile-pairs

// workspace layout (bytes) — all buffers written-before-read every call; no pre-zero needed
#define OFF_HSLAB    0ull                      // 8*64*160*4 = 327680
#define OFF_LCNTS    327680ull                 // 8*64*4 = 2048
#define OFF_CANDU    329728ull                 // 8*64*512*8 = 2097152
#define OFF_HISTG    2426880ull                // 8*4096*4 = 131072
#define OFF_CUMG     2557952ull                // 8*4097*4 = 131104
#define OFF_TINFO    2689056ull                // 32
#define OFF_CANDS    2689088ull                // 8*16384*8 = 1048576
#define OFF_BOXES    3737664ull                // 8*6016*16 = 770048
#define OFF_CNT      4507712ull                // 8*6016*4 = 192512 (zeroed in binsort prologue)
#define OFF_EDGES    4700224ull                // 8*6016*8*2 = 770048 -> 5470272 total

__device__ __forceinline__ int score_bin(float s) {
    int b = (int)(s * 4096.0f);          // *4096 exact (pow2) -> monotone
    return min(max(b, 0), NBINS - 1);
}

__device__ __forceinline__ float iou_of(float4 A, float4 Bv) {
    float ai = (A.z - A.x) * (A.w - A.y);
    float aj = (Bv.z - Bv.x) * (Bv.w - Bv.y);
    float yy1 = fmaxf(A.x, Bv.x), xx1 = fmaxf(A.y, Bv.y);
    float yy2 = fminf(A.z, Bv.z), xx2 = fminf(A.w, Bv.w);
    float inter = fmaxf(yy2 - yy1, 0.f) * fmaxf(xx2 - xx1, 0.f);
    float uni = (ai + aj) - inter;
    return (uni > 0.f) ? inter / uni : 0.f;
}

// ---------------- K1: stream probs; stage candidates (bin>=T0S) + 160-bin hist ----------------
// All outputs are per-block private slabs via plain stores: no global atomics, no pre-zeroing.
__global__ __launch_bounds__(256) void k_pass1(
        const float* __restrict__ probs, uint32_t* __restrict__ hslab,
        uint32_t* __restrict__ lcnts, uint64_t* __restrict__ candU) {
    __shared__ uint32_t h[NHB];
    __shared__ uint64_t lkey[LCAP];
    __shared__ uint32_t lcnt;
    int b = blockIdx.y, sub = blockIdx.x, tid = threadIdx.x;
    if (tid < NHB) h[tid] = 0;
    if (tid == 0) lcnt = 0;
    __syncthreads();
    const float4* p4 = (const float4*)(probs + (size_t)b * NA * 2);
    const int total = NA / 2;
    for (int q = sub * 256 + tid; q < total; q += NSUB * 256) {
        float4 v = p4[q];
        #pragma unroll
        for (int k = 0; k < 2; ++k) {
            float s = k ? v.w : v.y;
            int bin = score_bin(s);
            if (bin >= T0S) {                        // ~0.04% of anchors
                atomicAdd(&h[bin - T0S], 1u);
                uint32_t p = atomicAdd(&lcnt, 1u);
                if (p < LCAP) {
                    uint32_t sb = __float_as_uint(s);
                    lkey[p] = ((uint64_t)(~sb) << 32) | (uint32_t)(2 * q + k);
                }
            }
        }
    }
    __syncthreads();
    uint32_t* hs = hslab + ((size_t)b * NSUB + sub) * NHB;
    if (tid < NHB) hs[tid] = h[tid];
    if (tid == 0) lcnts[b * NSUB + sub] = lcnt;      // raw count (overflow detect in k_mid)
    uint64_t* cb = candU + ((size_t)b * NSUB + sub) * LCAP;
    uint32_t n = min(lcnt, (uint32_t)LCAP);
    for (uint32_t i = tid; i < n; i += 256) cb[i] = lkey[i];
}

// ---------------- K2: per-batch select (T, suffix-cum) + bin-scatter to candS ----------------
__global__ __launch_bounds__(1024) void k_mid(
        const float* __restrict__ probs, const uint32_t* __restrict__ hslab,
        const uint32_t* __restrict__ lcnts, const uint64_t* __restrict__ candU,
        uint32_t* __restrict__ histG, uint32_t* __restrict__ cumG,
        uint32_t* __restrict__ tinfo, uint64_t* __restrict__ candS) {
    int b = blockIdx.x, tid = threadIdx.x;
    __shared__ uint32_t hS[NHB];
    __shared__ uint32_t cS[NHB + 1];     // cS[i] = #anchors with bin >= T0S+i
    __shared__ uint32_t bc[NHB];
    __shared__ uint32_t hf[NBINS];       // fallback only
    __shared__ int Tsh;
    __shared__ uint32_t flag;
    if (tid == 0) flag = 0;
    for (int i = tid; i < NHB; i += 1024) {
        uint32_t s = 0;
        #pragma unroll 8
        for (int sub = 0; sub < NSUB; ++sub)
            s += hslab[((size_t)b * NSUB + sub) * NHB + i];
        hS[i] = s;
        bc[i] = 0;
    }
    if (tid < NSUB && lcnts[b * NSUB + tid] > LCAP) atomicOr(&flag, 1u);
    __syncthreads();
    if (tid == 0) {
        uint32_t acc = 0;
        cS[NHB] = 0;
        int T = -1;
        for (int i = NHB - 1; i >= 0; --i) {
            acc += hS[i];
            cS[i] = acc;
            if (T < 0 && acc >= PRE) T = T0S + i;
        }
        Tsh = T;
    }
    __syncthreads();
    int T = Tsh;
    uint32_t* gh = histG + (size_t)b * NBINS;
    uint32_t* gc = cumG + (size_t)b * (NBINS + 1);

    if (flag || T < 0) {
        // ---- exact fallback (never taken for this input): full recount ----
        for (int i = tid; i < NBINS; i += 1024) hf[i] = 0;
        __syncthreads();
        const float4* p4 = (const float4*)(probs + (size_t)b * NA * 2);
        for (int q = tid; q < NA / 2; q += 1024) {
            float4 v = p4[q];
            atomicAdd(&hf[score_bin(v.y)], 1u);
            atomicAdd(&hf[score_bin(v.w)], 1u);
        }
        __syncthreads();
        if (tid == 0) {
            uint32_t acc = 0;
            gc[NBINS] = 0;
            int Tf = 0;
            for (int bin = NBINS - 1; bin >= 0; --bin) {
                acc += hf[bin];
                gc[bin] = acc;
                if (Tf == 0 && acc >= PRE) Tf = bin;
            }
            tinfo[b] = (uint32_t)Tf;
            Tsh = Tf;
        }
        for (int i = tid; i < NBINS; i += 1024) gh[i] = hf[i];
        __syncthreads();
        T = Tsh;
        for (int i = tid; i < NBINS; i += 1024) hf[i] = 0;   // reuse as rank counters
        __syncthreads();
        uint64_t* cso = candS + (size_t)b * CANDCAP;
        for (int q = tid; q < NA / 2; q += 1024) {
            float4 v = p4[q];
            #pragma unroll
            for (int k = 0; k < 2; ++k) {
                float s = k ? v.w : v.y;
                int bin = score_bin(s);
                if (bin >= T) {
                    uint32_t r = atomicAdd(&hf[bin], 1u);
                    uint32_t pos = gc[bin + 1] + r;
                    if (pos < CANDCAP) {
                        uint32_t sb = __float_as_uint(s);
                        cso[pos] = ((uint64_t)(~sb) << 32) | (uint32_t)(2 * q + k);
                    }
                }
            }
        }
        return;
    }

    // ---- normal path: publish hist/cum for bins >= T0S, scatter candidates ----
    for (int i = tid; i < NHB; i += 1024) {
        gh[T0S + i] = hS[i];
        gc[T0S + 1 + i] = cS[i + 1];
    }
    if (tid == 0) { gc[T0S] = cS[0]; tinfo[b] = (uint32_t)T; }
    __syncthreads();
    uint64_t* cso = candS + (size_t)b * CANDCAP;
    for (int u = tid; u < NSUB * LCAP; u += 1024) {
        int sub = u >> 9, i = u & (LCAP - 1);
        if (i < (int)lcnts[b * NSUB + sub]) {
            uint64_t k = candU[((size_t)b * NSUB + sub) * LCAP + i];
            float s = __uint_as_float(~(uint32_t)(k >> 32));
            int bin = score_bin(s);
            if (bin >= T) {
                uint32_t r = atomicAdd(&bc[bin - T0S], 1u);
                uint32_t pos = cS[bin + 1 - T0S] + r;
                if (pos < CANDCAP) cso[pos] = k;
            }
        }
    }
}

// ---------------- K3: per-bin sort + gather + transform (also zeros cnt) ----------------
__global__ __launch_bounds__(256) void k_binsort(
        const uint64_t* __restrict__ candS, const uint32_t* __restrict__ tinfo,
        const uint32_t* __restrict__ histG, const uint32_t* __restrict__ cumG,
        const float* __restrict__ rpn_bbox, const float* __restrict__ anchors,
        float* __restrict__ boxes, uint4* __restrict__ cntz) {
    __shared__ uint64_t key[SEGCAP];
    int tid = threadIdx.x;
    {   // zero cnt region (consumed by the LATER k_edges — no barrier needed)
        int zi = (blockIdx.y * gridDim.x + blockIdx.x) * 256 + tid;
        if (zi < 12032) cntz[zi] = make_uint4(0u, 0u, 0u, 0u);
    }
    int b = blockIdx.y;
    int T = (int)tinfo[b];
    const uint32_t* gh = histG + (size_t)b * NBINS;
    const uint32_t* gc = cumG + (size_t)b * (NBINS + 1);
    const uint64_t* cs = candS + (size_t)b * CANDCAP;
    const float4* an4 = (const float4*)(anchors + (size_t)b * NA * 4);
    const float4* bb4 = (const float4*)(rpn_bbox + (size_t)b * NA * 4);
    float4* bx = (float4*)(boxes) + (size_t)b * PREP;

    for (int bin = T + blockIdx.x; bin < NBINS; bin += gridDim.x) {
        int n = (int)gh[bin];
        if (n == 0) continue;
        if (n > SEGCAP) n = SEGCAP;
        uint32_t base = gc[bin + 1];
        if (base >= PRE) continue;
        int P = 1; while (P < n) P <<= 1;
        for (int i = tid; i < P; i += 256)
            key[i] = (i < n) ? cs[base + i] : ~0ull;
        __syncthreads();
        for (int k = 2; k <= P; k <<= 1) {
            for (int j = k >> 1; j > 0; j >>= 1) {
                for (int i = tid; i < P; i += 256) {
                    int ixj = i ^ j;
                    if (ixj > i) {
                        uint64_t a = key[i], c = key[ixj];
                        bool up = ((i & k) == 0);
                        if ((a > c) == up) { key[i] = c; key[ixj] = a; }
                    }
                }
                __syncthreads();
            }
        }
        for (int r = tid; r < n; r += 256) {
            uint32_t pos = base + (uint32_t)r;
            if (pos < PRE) {
                uint32_t aidx = (uint32_t)(key[r] & 0xFFFFFFFFu);
                float4 a = an4[aidx];
                float4 d = bb4[aidx];
                float dy = d.x * 0.1f, dx = d.y * 0.1f, dh = d.z * 0.2f, dw = d.w * 0.2f;
                float h = a.z - a.x, w = a.w - a.y;
                float cy = a.x + 0.5f * h;  cy = cy + dy * h;
                float cx = a.y + 0.5f * w;  cx = cx + dx * w;
                h = h * expf(dh);
                w = w * expf(dw);
                float y1 = cy - 0.5f * h, x1 = cx - 0.5f * w;
                float y2 = y1 + h, x2 = x1 + w;
                float4 o;
                o.x = fminf(fmaxf(y1, 0.f), 1.f);
                o.y = fminf(fmaxf(x1, 0.f), 1.f);
                o.z = fminf(fmaxf(y2, 0.f), 1.f);
                o.w = fminf(fmaxf(x2, 0.f), 1.f);
                bx[pos] = o;
            }
        }
        __syncthreads();
    }
}

// ---------------- K4: overlap edges — 624 blocks, lean inner loop ----------------
__global__ __launch_bounds__(256) void k_edges(const float* __restrict__ boxes,
                                               uint32_t* __restrict__ cnt,
                                               uint16_t* __restrict__ edges) {
    int b = blockIdx.y;
    int t = blockIdx.x;
    int ti = 0, rem = t;
    while (rem >= NJT - ti) { rem -= NJT - ti; ++ti; }
    int tj = ti + rem;                       // ti <= tj < NJT
    __shared__ float4 sb[256];
    const float4* bx = (const float4*)(boxes) + (size_t)b * PREP;
    sb[threadIdx.x] = bx[ti * 256 + threadIdx.x];
    __syncthreads();
    int gj = tj * 256 + threadIdx.x;
    float4 Jb = bx[gj];
    float jy1 = Jb.x, jx1 = Jb.y, jy2 = Jb.z, jx2 = Jb.w;
    float aj = (jy2 - jy1) * (jx2 - jx1);
    float thr = 0.6f * aj;
    bool diag = (ti == tj);
    uint32_t* cb = cnt + (size_t)b * PREP;
    uint16_t* eb = edges + (size_t)b * PREP * ECAP;
    int gibase = ti * 256;
    #pragma unroll 4
    for (int it = 0; it < 256; ++it) {
        float4 I = sb[it];                   // broadcast, conflict-free
        float yy1 = fmaxf(jy1, I.x), xx1 = fmaxf(jx1, I.y);
        float yy2 = fminf(jy2, I.z), xx2 = fminf(jx2, I.w);
        float ih = fmaxf(yy2 - yy1, 0.f), iw = fmaxf(xx2 - xx1, 0.f);
        float inter = ih * iw;
        if (inter > thr) {                   // rare path
            int gi = gibase + it;
            if (!diag || gi < gj) {
                float ai = (I.z - I.x) * (I.w - I.y);
                float uni = (ai + aj) - inter;   // reference op order
                float iou = inter / uni;
                if (iou > NMS_THR) {
                    uint32_t slot = atomicAdd(&cb[gj], 1u);
                    if (slot < ECAP) eb[(size_t)gj * ECAP + slot] = (uint16_t)gi;
                }
            }
        }
    }
}

// ---------------- K5: keep-scan, lane-parallel resolution ----------------
__global__ __launch_bounds__(256) void k_scan(const float* __restrict__ boxes,
                                              const uint32_t* __restrict__ cnt,
                                              const uint16_t* __restrict__ edges,
                                              float* __restrict__ out) {
    int b = blockIdx.x;
    __shared__ uint8_t  cl[PREP];
    __shared__ uint32_t pr[PREP];
    __shared__ uint64_t km[NCHUNK];
    __shared__ uint16_t list[OUT_CNT];
    __shared__ int kcs;
    int tid = threadIdx.x;
    const uint32_t* cb = cnt + (size_t)b * PREP;
    const uint32_t* eb32 = (const uint32_t*)(edges + (size_t)b * PREP * ECAP);
    const uint4*    eb128 = (const uint4*)(edges + (size_t)b * PREP * ECAP);
    #pragma unroll 4
    for (int j = tid; j < PREP; j += 256) {
        uint32_t c = cb[j];
        cl[j] = (j < J0) ? (uint8_t)(c > 255u ? 255u : c) : (uint8_t)255;  // 255 = unknown
        pr[j] = eb32[j * 4];   // slots 0,1
    }
    __syncthreads();
    const float4* bx = (const float4*)(boxes) + (size_t)b * PREP;
    if (tid < 64) {
        int lane = tid;
        int kc = 0;
        for (int c0 = 0; c0 < NCHUNK; ++c0) {
            int base = c0 * 64;
            int j = base + lane;
            bool valid = j < PRE;
            uint64_t word = __ballot(valid);
            int cv = valid ? (int)cl[j] : 0;
            uint32_t prv = pr[j];
            uint4 ev = make_uint4(0u, 0u, 0u, 0u);
            bool manym = (cv >= 3 && cv <= ECAP);
            if (__ballot(manym)) { if (manym) ev = eb128[j]; }
            bool same = false, supB = false;
            bool hard = valid && (cv > ECAP);
            if (valid && cv > 0 && cv <= ECAP) {
                if (cv <= 2) {
                    int p0 = (int)(prv & 0xFFFFu);
                    int p1 = (int)(prv >> 16);
                    bool s1 = (cv == 2) && (p1 >= base);
                    same = (p0 >= base) || s1;
                    if (!same) {
                        supB = ((km[p0 >> 6] >> (p0 & 63)) & 1ull) != 0ull;
                        if (!supB && cv == 2)
                            supB = ((km[p1 >> 6] >> (p1 & 63)) & 1ull) != 0ull;
                    }
                } else {
                    int es[8] = { (int)(ev.x & 0xFFFFu), (int)(ev.x >> 16),
                                  (int)(ev.y & 0xFFFFu), (int)(ev.y >> 16),
                                  (int)(ev.z & 0xFFFFu), (int)(ev.z >> 16),
                                  (int)(ev.w & 0xFFFFu), (int)(ev.w >> 16) };
                    #pragma unroll
                    for (int k = 0; k < 8; ++k)
                        if (k < cv) same = same || (es[k] >= base);
                    if (!same) {
                        #pragma unroll
                        for (int k = 0; k < 8; ++k)
                            if (k < cv && !supB)
                                supB = ((km[es[k] >> 6] >> (es[k] & 63)) & 1ull) != 0ull;
                    }
                }
            }
            word &= ~__ballot(supB);
            uint64_t fix = __ballot(same || hard);
            while (fix) {
                int p = __ffsll((unsigned long long)fix) - 1;
                fix &= fix - 1;
                int jp = base + p;
                int cvp = __shfl(cv, p);
                bool sup = false;
                if (cvp <= ECAP) {
                    uint32_t prp = (uint32_t)__shfl((int)prv, p);
                    uint32_t evx = (uint32_t)__shfl((int)ev.x, p);
                    uint32_t evy = (uint32_t)__shfl((int)ev.y, p);
                    uint32_t evz = (uint32_t)__shfl((int)ev.z, p);
                    uint32_t evw = (uint32_t)__shfl((int)ev.w, p);
                    int es[8];
                    if (cvp <= 2) {
                        es[0] = (int)(prp & 0xFFFFu); es[1] = (int)(prp >> 16);
                        es[2] = es[3] = es[4] = es[5] = es[6] = es[7] = 0;
                    } else {
                        es[0] = (int)(evx & 0xFFFFu); es[1] = (int)(evx >> 16);
                        es[2] = (int)(evy & 0xFFFFu); es[3] = (int)(evy >> 16);
                        es[4] = (int)(evz & 0xFFFFu); es[5] = (int)(evz >> 16);
                        es[6] = (int)(evw & 0xFFFFu); es[7] = (int)(evw >> 16);
                    }
                    #pragma unroll
                    for (int k = 0; k < 8; ++k) {
                        if (k < cvp && !sup) {
                            int e = es[k];
                            bool kept = (e >= base)
                                ? (((word >> (e - base)) & 1ull) != 0ull)
                                : (((km[e >> 6] >> (e & 63)) & 1ull) != 0ull);
                            sup = sup || kept;
                        }
                    }
                } else {
                    float4 J = bx[jp];
                    bool any = false;
                    for (int t2 = lane; t2 < kc; t2 += 64)
                        if (iou_of(bx[list[t2]], J) > NMS_THR) any = true;
                    if (lane < p && ((word >> lane) & 1ull))
                        if (iou_of(bx[base + lane], J) > NMS_THR) any = true;
                    sup = (__ballot(any) != 0ull);
                }
                if (sup) word &= ~(1ull << p);
            }
            km[c0] = word;
            int pos = kc + __popcll(word & ((1ull << lane) - 1ull));
            if (((word >> lane) & 1ull) && pos < OUT_CNT) list[pos] = (uint16_t)j;
            kc += __popcll(word);
            if (kc >= OUT_CNT) { kc = OUT_CNT; break; }
        }
        if (lane == 0) kcs = kc;
    }
    __syncthreads();
    int kc = kcs;
    float4* ob = (float4*)(out) + (size_t)b * OUT_CNT;
    for (int r = tid; r < OUT_CNT; r += 256) {
        float4 o = make_float4(0.f, 0.f, 0.f, 0.f);
        if (r < kc) o = bx[list[r]];
        ob[r] = o;
    }
}

extern "C" void kernel_launch(void* const* d_in, const int* in_sizes, int n_in,
                              void* d_out, int out_size, void* d_ws, size_t ws_size,
                              hipStream_t stream) {
    const float* probs   = (const float*)d_in[0];
    const float* rpnbbox = (const float*)d_in[1];
    const float* anchors = (const float*)d_in[2];
    float* out = (float*)d_out;
    char* ws = (char*)d_ws;

    uint32_t* hslab = (uint32_t*)(ws + OFF_HSLAB);
    uint32_t* lcnts = (uint32_t*)(ws + OFF_LCNTS);
    uint64_t* candU = (uint64_t*)(ws + OFF_CANDU);
    uint32_t* histG = (uint32_t*)(ws + OFF_HISTG);
    uint32_t* cumG  = (uint32_t*)(ws + OFF_CUMG);
    uint32_t* tinfo = (uint32_t*)(ws + OFF_TINFO);
    uint64_t* candS = (uint64_t*)(ws + OFF_CANDS);
    float*    boxes = (float*)(ws + OFF_BOXES);
    uint32_t* cnt   = (uint32_t*)(ws + OFF_CNT);
    uint16_t* edges = (uint16_t*)(ws + OFF_EDGES);

    k_pass1<<<dim3(NSUB, NBATCH), 256, 0, stream>>>(probs, hslab, lcnts, candU);
    k_mid<<<NBATCH, 1024, 0, stream>>>(probs, hslab, lcnts, candU, histG, cumG, tinfo, candS);
    k_binsort<<<dim3(128, NBATCH), 256, 0, stream>>>(candS, tinfo, histG, cumG, rpnbbox, anchors,
                                                     boxes, (uint4*)(ws + OFF_CNT));
    k_edges<<<dim3(NTPE, NBATCH), 256, 0, stream>>>(boxes, cnt, edges);
    k_scan<<<NBATCH, 256, 0, stream>>>(boxes, cnt, edges, out);
}